// Round 1
// 423.439 us; speedup vs baseline: 1.0788x; 1.0788x over previous
//
#include <hip/hip_runtime.h>
#include <hip/hip_bf16.h>
#include <math.h>

#define BB 4
#define NQ 1024
#define NKV 4096
#define DMODEL 1024
#define NH 16
#define HD 64

typedef __attribute__((ext_vector_type(8))) short short8;
typedef __attribute__((ext_vector_type(4))) float floatx4;

__device__ __forceinline__ unsigned short f2bf(float f) {
    __hip_bfloat16 b = __float2bfloat16(f);
    return *reinterpret_cast<unsigned short*>(&b);
}

// pack two known-finite positive floats to bf16x2, round-half-up (5 VALU)
__device__ __forceinline__ unsigned int pack2bf_rhu(float a, float b) {
    unsigned ua = __builtin_bit_cast(unsigned, a) + 0x8000u;
    unsigned ub = __builtin_bit_cast(unsigned, b) + 0x8000u;
    return (ua >> 16) | (ub & 0xffff0000u);
}

// async global->LDS DMA, 16B/lane. Dest = wave-uniform base + lane*16.
__device__ __forceinline__ void gl_lds16(void* lds, const void* g) {
    __builtin_amdgcn_global_load_lds(
        (const __attribute__((address_space(1))) unsigned int*)g,
        (__attribute__((address_space(3))) unsigned int*)lds, 16, 0, 0);
}

// ---------------- mask: detect format + expand to additive, ONE kernel ---------
__global__ __launch_bounds__(1024) void maskprep2(const int* __restrict__ mask,
                                                  float* __restrict__ maskadd) {
    __shared__ int s;
    if (threadIdx.x == 0) s = 0;
    __syncthreads();
    int local = 0;
    for (int i = threadIdx.x; i < 4096; i += 1024)
        if (((const unsigned*)mask)[i] > 1u) local = 1;
    if (local) atomicOr(&s, 1);
    __syncthreads();
    const bool bytes = (s != 0);
    for (int i = threadIdx.x; i < BB * NKV; i += 1024) {
        bool m = bytes ? (((const unsigned char*)mask)[i] != 0) : (mask[i] != 0);
        maskadd[i] = m ? -1e30f : 0.0f;
    }
}

// ---------------- elementwise fp32 -> bf16 cast (8 elems/thread) ----------------
__global__ __launch_bounds__(256) void cast_bf16(const float* __restrict__ src,
                                                 unsigned short* __restrict__ dst,
                                                 int n) {
    int i = (blockIdx.x * 256 + threadIdx.x) * 8;
    if (i >= n) return;
    float4 a = *(const float4*)&src[i];
    float4 b = *(const float4*)&src[i + 4];
    short8 v;
    v[0] = (short)f2bf(a.x); v[1] = (short)f2bf(a.y);
    v[2] = (short)f2bf(a.z); v[3] = (short)f2bf(a.w);
    v[4] = (short)f2bf(b.x); v[5] = (short)f2bf(b.y);
    v[6] = (short)f2bf(b.z); v[7] = (short)f2bf(b.w);
    *(short8*)&dst[i] = v;
}

// ---------------- all 3 weight transposes in ONE launch -------------------------
__global__ __launch_bounds__(256) void transpose_cast3(
    const float* __restrict__ Wq, const float* __restrict__ Wkv,
    const float* __restrict__ Wproj,
    unsigned short* __restrict__ WqT, unsigned short* __restrict__ WkvT,
    unsigned short* __restrict__ WprojT)
{
    const float* src; unsigned short* dst; int N;
    if (blockIdx.z == 0)      { src = Wq;    dst = WqT;    N = DMODEL; }
    else if (blockIdx.z == 1) { src = Wkv;   dst = WkvT;   N = 2 * DMODEL; }
    else                      { src = Wproj; dst = WprojT; N = DMODEL; }
    if ((int)blockIdx.x * 64 >= N) return;
    const int K = DMODEL;
    __shared__ unsigned short t[64][72];
    int r0 = blockIdx.y * 64, c0 = blockIdx.x * 64;
    int tid = threadIdx.x;
#pragma unroll
    for (int i = 0; i < 4; i++) {
        int r = i * 16 + (tid >> 4), c = (tid & 15) * 4;
        float4 v = *(const float4*)&src[(size_t)(r0 + r) * N + c0 + c];
        t[c + 0][r] = f2bf(v.x); t[c + 1][r] = f2bf(v.y);
        t[c + 2][r] = f2bf(v.z); t[c + 3][r] = f2bf(v.w);
    }
    __syncthreads();
#pragma unroll
    for (int i = 0; i < 2; i++) {
        int rr = i * 32 + (tid >> 3), cc = (tid & 7) * 8;
        *(uint4*)&dst[(size_t)(c0 + rr) * K + r0 + cc] = *(uint4*)&t[rr][cc];
    }
}

// ---------------- bf16 MFMA GEMM: C = alpha * A @ Bt^T (proven R3) ----------------
template <int EPI>
__global__ __launch_bounds__(256) void gemm_mfma(
    const unsigned short* __restrict__ A,
    const unsigned short* __restrict__ Bt,
    const float* __restrict__ bias,
    unsigned short* __restrict__ o16,
    unsigned short* __restrict__ oT,
    float* __restrict__ o32,
    int M, int N, int K, float alpha, int m_out_base)
{
    extern __shared__ char smem[];
    unsigned short* As = (unsigned short*)smem;            // 512 chunks = 8KB
    unsigned short* Bs = (unsigned short*)(smem + 8192);   // 512 chunks = 8KB
    const int tid = threadIdx.x;
    const int wave = tid >> 6, lane = tid & 63;
    const int quad = lane >> 4, l16 = lane & 15;
    const int wm = wave >> 1, wn = wave & 1;
    const int m0 = blockIdx.y * 128, n0 = blockIdx.x * 128;

    const int c0 = wave * 64 + lane, c1 = c0 + 256;
    const int r0s = c0 >> 2, cc0 = (c0 & 3) ^ ((r0s >> 2) & 3);
    const int r1s = c1 >> 2, cc1 = (c1 & 3) ^ ((r1s >> 2) & 3);
    const unsigned short* ag0 = A + (size_t)(m0 + r0s) * K + cc0 * 8;
    const unsigned short* ag1 = A + (size_t)(m0 + r1s) * K + cc1 * 8;
    const unsigned short* bg0 = Bt + (size_t)(n0 + r0s) * K + cc0 * 8;
    const unsigned short* bg1 = Bt + (size_t)(n0 + r1s) * K + cc1 * 8;
    char* AldsW0 = (char*)As + (wave * 64) * 16;
    char* AldsW1 = (char*)As + (256 + wave * 64) * 16;
    char* BldsW0 = (char*)Bs + (wave * 64) * 16;
    char* BldsW1 = (char*)Bs + (256 + wave * 64) * 16;

    int achk[4], bchk[4];
#pragma unroll
    for (int i = 0; i < 4; i++) {
        int ra = wm * 64 + i * 16 + l16;
        achk[i] = ra * 4 + (quad ^ ((ra >> 2) & 3));
        int rb = wn * 64 + i * 16 + l16;
        bchk[i] = rb * 4 + (quad ^ ((rb >> 2) & 3));
    }

    floatx4 acc[4][4];
#pragma unroll
    for (int i = 0; i < 4; i++)
#pragma unroll
        for (int j = 0; j < 4; j++) acc[i][j] = (floatx4)0.0f;

    for (int kt = 0; kt < K; kt += 32) {
        __syncthreads();
        gl_lds16(AldsW0, ag0 + kt);
        gl_lds16(AldsW1, ag1 + kt);
        gl_lds16(BldsW0, bg0 + kt);
        gl_lds16(BldsW1, bg1 + kt);
        __syncthreads();
        short8 af[4], bfr[4];
#pragma unroll
        for (int i = 0; i < 4; i++) af[i] = *(const short8*)&As[achk[i] * 8];
#pragma unroll
        for (int j = 0; j < 4; j++) bfr[j] = *(const short8*)&Bs[bchk[j] * 8];
#pragma unroll
        for (int i = 0; i < 4; i++)
#pragma unroll
            for (int j = 0; j < 4; j++)
                acc[i][j] = __builtin_amdgcn_mfma_f32_16x16x32_bf16(
                    af[i], bfr[j], acc[i][j], 0, 0, 0);
    }

    const int rowbase = m0 + wm * 64;
    const int colbase = n0 + wn * 64;
    if (EPI == 0) {
#pragma unroll
        for (int i = 0; i < 4; i++)
#pragma unroll
            for (int r = 0; r < 4; r++) {
                size_t row = (size_t)(rowbase + i * 16 + quad * 4 + r);
#pragma unroll
                for (int j = 0; j < 4; j++)
                    o16[row * N + colbase + j * 16 + l16] =
                        f2bf(acc[i][j][r] * alpha);
            }
    } else if (EPI == 2) {
        float bv[4];
#pragma unroll
        for (int j = 0; j < 4; j++) bv[j] = bias[colbase + j * 16 + l16];
#pragma unroll
        for (int i = 0; i < 4; i++)
#pragma unroll
            for (int r = 0; r < 4; r++) {
                size_t row = (size_t)(rowbase + i * 16 + quad * 4 + r);
#pragma unroll
                for (int j = 0; j < 4; j++)
                    o32[row * N + colbase + j * 16 + l16] = acc[i][j][r] + bv[j];
            }
    } else {  // EPI == 1: N=2048; cols<1024 -> Kb natural, cols>=1024 -> VTb^T
        if (n0 < DMODEL) {
#pragma unroll
            for (int i = 0; i < 4; i++)
#pragma unroll
                for (int r = 0; r < 4; r++) {
                    int gm = m_out_base + rowbase + i * 16 + quad * 4 + r;
                    int b = gm >> 12, key = gm & (NKV - 1);
                    size_t row = (size_t)(b * NKV + key);
#pragma unroll
                    for (int j = 0; j < 4; j++)
                        o16[row * DMODEL + colbase + j * 16 + l16] =
                            f2bf(acc[i][j][r]);
                }
        } else {
            __syncthreads();
            unsigned short (*scr)[72] =
                (unsigned short(*)[72])(smem + wave * 64 * 72 * 2);
#pragma unroll
            for (int i = 0; i < 4; i++)
#pragma unroll
                for (int j = 0; j < 4; j++)
#pragma unroll
                    for (int r = 0; r < 4; r++)
                        scr[j * 16 + l16][i * 16 + quad * 4 + r] =
                            f2bf(acc[i][j][r]);
            __syncthreads();
            int gmb = m_out_base + rowbase;
            int b = gmb >> 12, key0 = gmb & (NKV - 1);
            int d0 = colbase - DMODEL;
#pragma unroll
            for (int p = 0; p < 8; p++) {
                int rr = p * 8 + (lane >> 3), ch = lane & 7;
                *(uint4*)&oT[((size_t)(b * DMODEL + d0 + rr)) * NKV + key0 + ch * 8] =
                    *(uint4*)&scr[rr][ch * 8];
            }
        }
    }
}

// ---------------- fused flash attention v5: 128-row blocks, no-tail grid --------
// v4 (proven) ran 1024 blocks x 256thr with 3 resident/CU -> two scheduling
// rounds (768 @ 37.5% occ, then 256 @ 12.5%) = measured 25.7% avg occupancy;
// half the wall time at 2 waves/SIMD cannot hide the serial
// MFMA->exp2->LDS->MFMA chain. v5: 512 threads / 128 q-rows per block ->
// grid = 8 x 64 = 512 blocks = EXACTLY 2/CU (LDS 59,904B x2 <= 160KB), one
// round, steady 4 waves/SIMD. Per-wave inner loop is identical to v4 (each
// wave owns 16 q-rows); K/V staging spread over 2x threads (1 uint4 each);
// K/V global traffic per q-row halves. XCD swizzle re-derived: 8 q-tiles of
// one (b,h) per XCD.
__global__ __launch_bounds__(512, 4) void attn_mfma5(
    const unsigned short* __restrict__ Qb,   // (B,NQ,D) bf16, scaled
    const unsigned short* __restrict__ Kb,   // (B,NKV,D) bf16
    const unsigned short* __restrict__ VTb,  // (B,D,NKV) bf16
    const float* __restrict__ maskadd,       // (B,NKV) 0 / -1e30
    unsigned short* __restrict__ x)          // (B,NQ,D) bf16
{
    const int lid = blockIdx.y * gridDim.x + blockIdx.x;  // [0,512)
    const int xcd = lid & 7, slot = lid >> 3;             // slot in [0,64)
    const int bh = xcd * 8 + (slot & 7);    // 8 q-tiles of one (b,h) per XCD
    const int b = bh >> 4, h = bh & 15;
    const int m0 = (slot >> 3) * 128;
    const int tid = threadIdx.x;
    const int wave = tid >> 6, lane = tid & 63;
    const int quad = lane >> 4, l16 = lane & 15;

    __shared__ __align__(16) unsigned short qp_s[128][72];    // Q stage -> P^T
    __shared__ __align__(16) unsigned short k_s[2][64][72];   // [key][d]
    __shared__ __align__(16) unsigned short vT_s[2][80][72];  // [d][key]; 64..79=1.0

    // ones rows (both buffers), written once, never overwritten
    for (int t = tid; t < 2 * 16 * 72; t += 512) {
        int bufi = t / (16 * 72), rem = t % (16 * 72);
        vT_s[bufi][64 + rem / 72][rem % 72] = 0x3F80;  // bf16 1.0
    }
    // stage Q tile (128 x 64)
    {
        const int qr = tid >> 2, qc = (tid & 3) * 16;
        const unsigned short* src =
            Qb + ((size_t)(b * NQ + m0 + qr)) * DMODEL + h * HD + qc;
        *(uint4*)&qp_s[qr][qc]     = *(const uint4*)src;
        *(uint4*)&qp_s[qr][qc + 8] = *(const uint4*)(src + 8);
    }

    const float* madd_row = maskadd + b * NKV;
    const unsigned short* Kbase = Kb + ((size_t)b * NKV) * DMODEL + h * HD;
    const unsigned short* Vbase = VTb + ((size_t)(b * DMODEL + h * HD)) * NKV;

    const int kr = tid >> 3, kc = (tid & 7) * 8;  // K/V staging: 1 uint4 each

    // prologue: stage tile 0 into buf 0
    {
        const unsigned short* ks = Kbase + (size_t)kr * DMODEL + kc;
        uint4 a0 = *(const uint4*)ks;
        const unsigned short* vs = Vbase + (size_t)kr * NKV + kc;
        uint4 b0 = *(const uint4*)vs;
        *(uint4*)&k_s[0][kr][kc]  = a0;
        *(uint4*)&vT_s[0][kr][kc] = b0;
    }
    __syncthreads();

    // hoist Q B-frags; qp_s rows become per-wave P^T strips
    short8 bq0 = *(const short8*)&qp_s[wave * 16 + l16][quad * 8];
    short8 bq1 = *(const short8*)&qp_s[wave * 16 + l16][32 + quad * 8];

    floatx4 o[4], ol;          // O and the l-column accumulator
#pragma unroll
    for (int f = 0; f < 4; f++) o[f] = (floatx4)0.0f;
    ol = (floatx4)0.0f;
    unsigned short* prow = &qp_s[wave * 16 + l16][0];

    for (int i = 0; i < NKV / 64; i++) {
        const int buf = i & 1;
        uint4 pk, pv;
        const bool pf = (i < NKV / 64 - 1);
        if (pf) {
            int nn = (i + 1) * 64;
            pk = *(const uint4*)(Kbase + (size_t)(nn + kr) * DMODEL + kc);
            pv = *(const uint4*)(Vbase + (size_t)kr * NKV + nn + kc);
        }
        if (i) __syncthreads();

        // S^T = K.Q^T : key = f*16 + quad*4 + r, q = l16 (in log2 units)
        floatx4 st[4];
#pragma unroll
        for (int f = 0; f < 4; f++) {
            short8 ak0 = *(const short8*)&k_s[buf][f * 16 + l16][quad * 8];
            short8 ak1 = *(const short8*)&k_s[buf][f * 16 + l16][32 + quad * 8];
            floatx4 t = (floatx4)0.0f;
            t = __builtin_amdgcn_mfma_f32_16x16x32_bf16(ak0, bq0, t, 0, 0, 0);
            t = __builtin_amdgcn_mfma_f32_16x16x32_bf16(ak1, bq1, t, 0, 0, 0);
            st[f] = t;
        }

        int n0 = i * 64;
        // P = exp2(S^T + mask), packed round-half-up, straight to LDS
#pragma unroll
        for (int f = 0; f < 4; f++) {
            float4 mv = *(const float4*)&madd_row[n0 + f * 16 + quad * 4];
            float p0 = __builtin_amdgcn_exp2f(st[f][0] + mv.x);
            float p1 = __builtin_amdgcn_exp2f(st[f][1] + mv.y);
            float p2 = __builtin_amdgcn_exp2f(st[f][2] + mv.z);
            float p3 = __builtin_amdgcn_exp2f(st[f][3] + mv.w);
            uint2 pw;
            pw.x = pack2bf_rhu(p0, p1);
            pw.y = pack2bf_rhu(p2, p3);
            *(uint2*)&prow[f * 16 + quad * 4] = pw;  // 4 consecutive keys
        }

        // drain this wave's P^T writes before aliasing A-frag reads
        asm volatile("s_waitcnt lgkmcnt(0)" ::: "memory");
        short8 ap0 = *(const short8*)&qp_s[wave * 16 + l16][quad * 8];
        short8 ap1 = *(const short8*)&qp_s[wave * 16 + l16][32 + quad * 8];
        // O += P.V across f=0..3; f=4 (ones rows) accumulates l
#pragma unroll
        for (int f = 0; f < 4; f++) {
            short8 bv0 = *(const short8*)&vT_s[buf][f * 16 + l16][quad * 8];
            short8 bv1 = *(const short8*)&vT_s[buf][f * 16 + l16][32 + quad * 8];
            o[f] = __builtin_amdgcn_mfma_f32_16x16x32_bf16(ap0, bv0, o[f], 0, 0, 0);
            o[f] = __builtin_amdgcn_mfma_f32_16x16x32_bf16(ap1, bv1, o[f], 0, 0, 0);
        }
        {
            short8 bv0 = *(const short8*)&vT_s[buf][64 + l16][quad * 8];
            short8 bv1 = *(const short8*)&vT_s[buf][64 + l16][32 + quad * 8];
            ol = __builtin_amdgcn_mfma_f32_16x16x32_bf16(ap0, bv0, ol, 0, 0, 0);
            ol = __builtin_amdgcn_mfma_f32_16x16x32_bf16(ap1, bv1, ol, 0, 0, 0);
        }

        if (pf) {
            *(uint4*)&k_s[buf ^ 1][kr][kc]  = pk;
            *(uint4*)&vT_s[buf ^ 1][kr][kc] = pv;
        }
    }

    // epilogue: ol[r] = l for row q = quad*4 + r, valid at every lane
#pragma unroll
    for (int r = 0; r < 4; r++) {
        float inv = 1.0f / ol[r];
        size_t row = (size_t)(b * NQ + m0 + wave * 16 + quad * 4 + r);
#pragma unroll
        for (int f = 0; f < 4; f++) {
            unsigned u = __builtin_bit_cast(unsigned, o[f][r] * inv) + 0x8000u;
            x[row * DMODEL + h * HD + f * 16 + l16] = (unsigned short)(u >> 16);
        }
    }
}

extern "C" void kernel_launch(void* const* d_in, const int* in_sizes, int n_in,
                              void* d_out, int out_size, void* d_ws, size_t ws_size,
                              hipStream_t stream) {
    const float* q     = (const float*)d_in[0];
    const float* kv    = (const float*)d_in[1];
    const int*   mask  = (const int*)d_in[2];
    const float* Wq    = (const float*)d_in[3];
    const float* Wkv   = (const float*)d_in[4];
    const float* Wproj = (const float*)d_in[5];
    const float* bproj = (const float*)d_in[6];
    float* out = (float*)d_out;

    // ws layout, total 92,340,480 B <= proven 92,540,480 (R2)
    char* ws = (char*)d_ws;
    size_t o = 0;
    o += 256;  // (reserved)
    float* maskadd   = (float*)(ws + o); o += 65536;
    unsigned short* Qb     = (unsigned short*)(ws + o); o += (size_t)BB * NQ * DMODEL * 2;   // 8 MB
    unsigned short* Kb     = (unsigned short*)(ws + o); o += (size_t)BB * NKV * DMODEL * 2;  // 32 MB
    unsigned short* VTb    = (unsigned short*)(ws + o); o += (size_t)BB * NKV * DMODEL * 2;  // 32 MB
    unsigned short* WprojT = (unsigned short*)(ws + o); o += (size_t)DMODEL * DMODEL * 2;    // 2 MB
    unsigned short* qbf    = (unsigned short*)(ws + o);  // 8 MB, dead after q-proj
    unsigned short* xb     = qbf;                        // alias: written by attn later
    o += (size_t)BB * NQ * DMODEL * 2;
    unsigned short* WqT    = (unsigned short*)(ws + o); o += (size_t)DMODEL * DMODEL * 2;     // 2 MB
    unsigned short* WkvT   = (unsigned short*)(ws + o); o += (size_t)DMODEL * 2 * DMODEL * 2; // 4 MB
    unsigned short* kvh = (unsigned short*)d_out;  // kv bf16 staged through d_out

    hipLaunchKernelGGL(maskprep2, dim3(1), dim3(1024), 0, stream, mask, maskadd);
    hipLaunchKernelGGL(transpose_cast3, dim3(32, DMODEL / 64, 3), dim3(256), 0, stream,
                       Wq, Wkv, Wproj, WqT, WkvT, WprojT);

    // Qb = bf16((q @ Wq) * hd^-0.5 * log2(e))  [log2e folded for native exp2]
    hipLaunchKernelGGL(cast_bf16, dim3(BB * NQ * DMODEL / 2048), dim3(256), 0, stream,
                       q, qbf, BB * NQ * DMODEL);
    hipLaunchKernelGGL((gemm_mfma<0>), dim3(DMODEL / 128, BB * NQ / 128), dim3(256), 16384, stream,
                       qbf, WqT, (const float*)nullptr, Qb, (unsigned short*)nullptr,
                       (float*)nullptr, BB * NQ, DMODEL, DMODEL, 0.125f * 1.44269504f, 0);

    // kv projection in two halves, bf16 A staged in d_out
    const int HALF_ROWS = BB * NKV / 2;  // 8192
    for (int half = 0; half < 2; half++) {
        const float* src = kv + (size_t)half * HALF_ROWS * DMODEL;
        hipLaunchKernelGGL(cast_bf16, dim3(HALF_ROWS * DMODEL / 2048), dim3(256), 0, stream,
                           src, kvh, HALF_ROWS * DMODEL);
        hipLaunchKernelGGL((gemm_mfma<1>), dim3(2 * DMODEL / 128, HALF_ROWS / 128), dim3(256), 36864, stream,
                           kvh, WkvT, (const float*)nullptr, Kb, VTb,
                           (float*)nullptr, HALF_ROWS, 2 * DMODEL, DMODEL, 1.0f, half * HALF_ROWS);
    }

    // fused flash attention v5 -> xb (bf16)
    hipLaunchKernelGGL(attn_mfma5, dim3(NQ / 128, BB * NH), dim3(512), 0, stream,
                       Qb, Kb, VTb, maskadd, xb);

    // out = xb @ Wproj + bproj (fp32)
    hipLaunchKernelGGL((gemm_mfma<2>), dim3(DMODEL / 128, BB * NQ / 128), dim3(256), 16384, stream,
                       xb, WprojT, bproj, (unsigned short*)nullptr, (unsigned short*)nullptr,
                       out, BB * NQ, DMODEL, DMODEL, 1.0f, 0);
}

// Round 2
// 422.707 us; speedup vs baseline: 1.0807x; 1.0017x over previous
//
#include <hip/hip_runtime.h>
#include <hip/hip_bf16.h>
#include <math.h>

#define BB 4
#define NQ 1024
#define NKV 4096
#define DMODEL 1024
#define NH 16
#define HD 64

typedef __attribute__((ext_vector_type(8))) short short8;
typedef __attribute__((ext_vector_type(4))) float floatx4;

__device__ __forceinline__ unsigned short f2bf(float f) {
    __hip_bfloat16 b = __float2bfloat16(f);
    return *reinterpret_cast<unsigned short*>(&b);
}

// pack two known-finite positive floats to bf16x2, round-half-up (5 VALU)
__device__ __forceinline__ unsigned int pack2bf_rhu(float a, float b) {
    unsigned ua = __builtin_bit_cast(unsigned, a) + 0x8000u;
    unsigned ub = __builtin_bit_cast(unsigned, b) + 0x8000u;
    return (ua >> 16) | (ub & 0xffff0000u);
}

// async global->LDS DMA, 16B/lane. Dest = wave-uniform base + lane*16.
__device__ __forceinline__ void gl_lds16(void* lds, const void* g) {
    __builtin_amdgcn_global_load_lds(
        (const __attribute__((address_space(1))) unsigned int*)g,
        (__attribute__((address_space(3))) unsigned int*)lds, 16, 0, 0);
}

// ---------------- mask: detect format + expand to additive, ONE kernel ---------
__global__ __launch_bounds__(1024) void maskprep2(const int* __restrict__ mask,
                                                  float* __restrict__ maskadd) {
    __shared__ int s;
    if (threadIdx.x == 0) s = 0;
    __syncthreads();
    int local = 0;
    for (int i = threadIdx.x; i < 4096; i += 1024)
        if (((const unsigned*)mask)[i] > 1u) local = 1;
    if (local) atomicOr(&s, 1);
    __syncthreads();
    const bool bytes = (s != 0);
    for (int i = threadIdx.x; i < BB * NKV; i += 1024) {
        bool m = bytes ? (((const unsigned char*)mask)[i] != 0) : (mask[i] != 0);
        maskadd[i] = m ? -1e30f : 0.0f;
    }
}

// ---------------- elementwise fp32 -> bf16 cast (8 elems/thread) ----------------
__global__ __launch_bounds__(256) void cast_bf16(const float* __restrict__ src,
                                                 unsigned short* __restrict__ dst,
                                                 int n) {
    int i = (blockIdx.x * 256 + threadIdx.x) * 8;
    if (i >= n) return;
    float4 a = *(const float4*)&src[i];
    float4 b = *(const float4*)&src[i + 4];
    short8 v;
    v[0] = (short)f2bf(a.x); v[1] = (short)f2bf(a.y);
    v[2] = (short)f2bf(a.z); v[3] = (short)f2bf(a.w);
    v[4] = (short)f2bf(b.x); v[5] = (short)f2bf(b.y);
    v[6] = (short)f2bf(b.z); v[7] = (short)f2bf(b.w);
    *(short8*)&dst[i] = v;
}

// ---------------- all 3 weight transposes in ONE launch -------------------------
__global__ __launch_bounds__(256) void transpose_cast3(
    const float* __restrict__ Wq, const float* __restrict__ Wkv,
    const float* __restrict__ Wproj,
    unsigned short* __restrict__ WqT, unsigned short* __restrict__ WkvT,
    unsigned short* __restrict__ WprojT)
{
    const float* src; unsigned short* dst; int N;
    if (blockIdx.z == 0)      { src = Wq;    dst = WqT;    N = DMODEL; }
    else if (blockIdx.z == 1) { src = Wkv;   dst = WkvT;   N = 2 * DMODEL; }
    else                      { src = Wproj; dst = WprojT; N = DMODEL; }
    if ((int)blockIdx.x * 64 >= N) return;
    const int K = DMODEL;
    __shared__ unsigned short t[64][72];
    int r0 = blockIdx.y * 64, c0 = blockIdx.x * 64;
    int tid = threadIdx.x;
#pragma unroll
    for (int i = 0; i < 4; i++) {
        int r = i * 16 + (tid >> 4), c = (tid & 15) * 4;
        float4 v = *(const float4*)&src[(size_t)(r0 + r) * N + c0 + c];
        t[c + 0][r] = f2bf(v.x); t[c + 1][r] = f2bf(v.y);
        t[c + 2][r] = f2bf(v.z); t[c + 3][r] = f2bf(v.w);
    }
    __syncthreads();
#pragma unroll
    for (int i = 0; i < 2; i++) {
        int rr = i * 32 + (tid >> 3), cc = (tid & 7) * 8;
        *(uint4*)&dst[(size_t)(c0 + rr) * K + r0 + cc] = *(uint4*)&t[rr][cc];
    }
}

// ---------------- bf16 MFMA GEMM: C = alpha * A @ Bt^T (proven R3) ----------------
template <int EPI>
__global__ __launch_bounds__(256) void gemm_mfma(
    const unsigned short* __restrict__ A,
    const unsigned short* __restrict__ Bt,
    const float* __restrict__ bias,
    unsigned short* __restrict__ o16,
    unsigned short* __restrict__ oT,
    float* __restrict__ o32,
    int M, int N, int K, float alpha, int m_out_base)
{
    extern __shared__ char smem[];
    unsigned short* As = (unsigned short*)smem;            // 512 chunks = 8KB
    unsigned short* Bs = (unsigned short*)(smem + 8192);   // 512 chunks = 8KB
    const int tid = threadIdx.x;
    const int wave = tid >> 6, lane = tid & 63;
    const int quad = lane >> 4, l16 = lane & 15;
    const int wm = wave >> 1, wn = wave & 1;
    const int m0 = blockIdx.y * 128, n0 = blockIdx.x * 128;

    const int c0 = wave * 64 + lane, c1 = c0 + 256;
    const int r0s = c0 >> 2, cc0 = (c0 & 3) ^ ((r0s >> 2) & 3);
    const int r1s = c1 >> 2, cc1 = (c1 & 3) ^ ((r1s >> 2) & 3);
    const unsigned short* ag0 = A + (size_t)(m0 + r0s) * K + cc0 * 8;
    const unsigned short* ag1 = A + (size_t)(m0 + r1s) * K + cc1 * 8;
    const unsigned short* bg0 = Bt + (size_t)(n0 + r0s) * K + cc0 * 8;
    const unsigned short* bg1 = Bt + (size_t)(n0 + r1s) * K + cc1 * 8;
    char* AldsW0 = (char*)As + (wave * 64) * 16;
    char* AldsW1 = (char*)As + (256 + wave * 64) * 16;
    char* BldsW0 = (char*)Bs + (wave * 64) * 16;
    char* BldsW1 = (char*)Bs + (256 + wave * 64) * 16;

    int achk[4], bchk[4];
#pragma unroll
    for (int i = 0; i < 4; i++) {
        int ra = wm * 64 + i * 16 + l16;
        achk[i] = ra * 4 + (quad ^ ((ra >> 2) & 3));
        int rb = wn * 64 + i * 16 + l16;
        bchk[i] = rb * 4 + (quad ^ ((rb >> 2) & 3));
    }

    floatx4 acc[4][4];
#pragma unroll
    for (int i = 0; i < 4; i++)
#pragma unroll
        for (int j = 0; j < 4; j++) acc[i][j] = (floatx4)0.0f;

    for (int kt = 0; kt < K; kt += 32) {
        __syncthreads();
        gl_lds16(AldsW0, ag0 + kt);
        gl_lds16(AldsW1, ag1 + kt);
        gl_lds16(BldsW0, bg0 + kt);
        gl_lds16(BldsW1, bg1 + kt);
        __syncthreads();
        short8 af[4], bfr[4];
#pragma unroll
        for (int i = 0; i < 4; i++) af[i] = *(const short8*)&As[achk[i] * 8];
#pragma unroll
        for (int j = 0; j < 4; j++) bfr[j] = *(const short8*)&Bs[bchk[j] * 8];
#pragma unroll
        for (int i = 0; i < 4; i++)
#pragma unroll
            for (int j = 0; j < 4; j++)
                acc[i][j] = __builtin_amdgcn_mfma_f32_16x16x32_bf16(
                    af[i], bfr[j], acc[i][j], 0, 0, 0);
    }

    const int rowbase = m0 + wm * 64;
    const int colbase = n0 + wn * 64;
    if (EPI == 0) {
#pragma unroll
        for (int i = 0; i < 4; i++)
#pragma unroll
            for (int r = 0; r < 4; r++) {
                size_t row = (size_t)(rowbase + i * 16 + quad * 4 + r);
#pragma unroll
                for (int j = 0; j < 4; j++)
                    o16[row * N + colbase + j * 16 + l16] =
                        f2bf(acc[i][j][r] * alpha);
            }
    } else if (EPI == 2) {
        float bv[4];
#pragma unroll
        for (int j = 0; j < 4; j++) bv[j] = bias[colbase + j * 16 + l16];
#pragma unroll
        for (int i = 0; i < 4; i++)
#pragma unroll
            for (int r = 0; r < 4; r++) {
                size_t row = (size_t)(rowbase + i * 16 + quad * 4 + r);
#pragma unroll
                for (int j = 0; j < 4; j++)
                    o32[row * N + colbase + j * 16 + l16] = acc[i][j][r] + bv[j];
            }
    } else {  // EPI == 1: N=2048; cols<1024 -> Kb natural, cols>=1024 -> VTb^T
        if (n0 < DMODEL) {
#pragma unroll
            for (int i = 0; i < 4; i++)
#pragma unroll
                for (int r = 0; r < 4; r++) {
                    int gm = m_out_base + rowbase + i * 16 + quad * 4 + r;
                    int b = gm >> 12, key = gm & (NKV - 1);
                    size_t row = (size_t)(b * NKV + key);
#pragma unroll
                    for (int j = 0; j < 4; j++)
                        o16[row * DMODEL + colbase + j * 16 + l16] =
                            f2bf(acc[i][j][r]);
                }
        } else {
            __syncthreads();
            unsigned short (*scr)[72] =
                (unsigned short(*)[72])(smem + wave * 64 * 72 * 2);
#pragma unroll
            for (int i = 0; i < 4; i++)
#pragma unroll
                for (int j = 0; j < 4; j++)
#pragma unroll
                    for (int r = 0; r < 4; r++)
                        scr[j * 16 + l16][i * 16 + quad * 4 + r] =
                            f2bf(acc[i][j][r]);
            __syncthreads();
            int gmb = m_out_base + rowbase;
            int b = gmb >> 12, key0 = gmb & (NKV - 1);
            int d0 = colbase - DMODEL;
#pragma unroll
            for (int p = 0; p < 8; p++) {
                int rr = p * 8 + (lane >> 3), ch = lane & 7;
                *(uint4*)&oT[((size_t)(b * DMODEL + d0 + rr)) * NKV + key0 + ch * 8] =
                    *(uint4*)&scr[rr][ch * 8];
            }
        }
    }
}

// ---------------- fused flash attention v6: K/V frags hoisted to regs ----------
// v5 post-mortem: LDS-op-issue-bound. 16 waves/CU x ~290 cy of ds ops per
// KV-iter ~= 4600 cy/CU/iter == measured 4820. Dominant term: K-frag (8KB)
// + V-frag (10KB) LDS reads are WAVE-INVARIANT yet re-read by all 8 waves.
// v6: 4 waves x 32 q-rows (2 strips of 16). Each wave hoists ak[4][2] and
// bv[4][2] into regs ONCE per KV-tile, reuses across both strips -> shared
// frag traffic halves per q-row; per-CU ds cycles ~2500/iter. Also drop the
// ones-rows/ol-MFMA denominator: accumulate per-lane VALU sum of the SAME
// rounded bf16 P values (numerator/denominator consistency preserved),
// cross-quad reduce at epilogue (2 shfl_xor + 4 shfl, once). LDS 55.3KB,
// 2 blocks/CU = 8 waves/CU (occupancy drop is fine: limiter is per-CU LDS
// bandwidth, not latency).
__global__ __launch_bounds__(256, 2) void attn_mfma6(
    const unsigned short* __restrict__ Qb,   // (B,NQ,D) bf16, scaled
    const unsigned short* __restrict__ Kb,   // (B,NKV,D) bf16
    const unsigned short* __restrict__ VTb,  // (B,D,NKV) bf16
    const float* __restrict__ maskadd,       // (B,NKV) 0 / -1e30
    unsigned short* __restrict__ x)          // (B,NQ,D) bf16
{
    const int lid = blockIdx.y * gridDim.x + blockIdx.x;  // [0,512)
    const int xcd = lid & 7, slot = lid >> 3;             // slot in [0,64)
    const int bh = xcd * 8 + (slot & 7);    // 8 q-tiles of one (b,h) per XCD
    const int b = bh >> 4, h = bh & 15;
    const int m0 = (slot >> 3) * 128;
    const int tid = threadIdx.x;
    const int wave = tid >> 6, lane = tid & 63;
    const int quad = lane >> 4, l16 = lane & 15;

    __shared__ __align__(16) unsigned short qp_s[128][72];    // Q stage -> P^T
    __shared__ __align__(16) unsigned short k_s[2][64][72];   // [key][d]
    __shared__ __align__(16) unsigned short vT_s[2][64][72];  // [d][key]

    // stage Q tile (128 x 64): 4 uint4 per thread
    {
        const int qr = tid >> 1, qc = (tid & 1) * 32;
        const unsigned short* src =
            Qb + ((size_t)(b * NQ + m0 + qr)) * DMODEL + h * HD + qc;
        *(uint4*)&qp_s[qr][qc]      = *(const uint4*)src;
        *(uint4*)&qp_s[qr][qc + 8]  = *(const uint4*)(src + 8);
        *(uint4*)&qp_s[qr][qc + 16] = *(const uint4*)(src + 16);
        *(uint4*)&qp_s[qr][qc + 24] = *(const uint4*)(src + 24);
    }

    const float* madd_row = maskadd + b * NKV;
    const unsigned short* Kbase = Kb + ((size_t)b * NKV) * DMODEL + h * HD;
    const unsigned short* Vbase = VTb + ((size_t)(b * DMODEL + h * HD)) * NKV;

    const int kr = tid >> 2, kc = (tid & 3) * 16;  // K/V staging: 2 uint4 each

    // prologue: stage K/V tile 0 into buf 0
    {
        const unsigned short* ks = Kbase + (size_t)kr * DMODEL + kc;
        uint4 a0 = *(const uint4*)ks, a1 = *(const uint4*)(ks + 8);
        const unsigned short* vs = Vbase + (size_t)kr * NKV + kc;
        uint4 b0 = *(const uint4*)vs, b1 = *(const uint4*)(vs + 8);
        *(uint4*)&k_s[0][kr][kc]      = a0;
        *(uint4*)&k_s[0][kr][kc + 8]  = a1;
        *(uint4*)&vT_s[0][kr][kc]     = b0;
        *(uint4*)&vT_s[0][kr][kc + 8] = b1;
    }
    __syncthreads();

    // hoist Q B-frags for both strips; qp_s rows become per-wave P^T strips
    short8 bq[2][2];
#pragma unroll
    for (int s = 0; s < 2; s++) {
        bq[s][0] = *(const short8*)&qp_s[wave * 32 + s * 16 + l16][quad * 8];
        bq[s][1] = *(const short8*)&qp_s[wave * 32 + s * 16 + l16][32 + quad * 8];
    }

    floatx4 o[2][4];
#pragma unroll
    for (int s = 0; s < 2; s++)
#pragma unroll
        for (int f = 0; f < 4; f++) o[s][f] = (floatx4)0.0f;
    float lsum[2] = {0.0f, 0.0f};
    unsigned short* prow0 = &qp_s[wave * 32 + l16][0];
    unsigned short* prow1 = &qp_s[wave * 32 + 16 + l16][0];

    for (int i = 0; i < NKV / 64; i++) {
        const int buf = i & 1;
        uint4 pk0, pk1, pv0, pv1;
        const bool pf = (i < NKV / 64 - 1);
        if (pf) {
            int nn = (i + 1) * 64;
            const unsigned short* ks = Kbase + (size_t)(nn + kr) * DMODEL + kc;
            pk0 = *(const uint4*)ks; pk1 = *(const uint4*)(ks + 8);
            const unsigned short* vs = Vbase + (size_t)kr * NKV + nn + kc;
            pv0 = *(const uint4*)vs; pv1 = *(const uint4*)(vs + 8);
        }
        if (i) __syncthreads();

        // hoist the wave-invariant K/V fragments ONCE, reuse across strips
        short8 ak[4][2], bv[4][2];
#pragma unroll
        for (int f = 0; f < 4; f++) {
            ak[f][0] = *(const short8*)&k_s[buf][f * 16 + l16][quad * 8];
            ak[f][1] = *(const short8*)&k_s[buf][f * 16 + l16][32 + quad * 8];
            bv[f][0] = *(const short8*)&vT_s[buf][f * 16 + l16][quad * 8];
            bv[f][1] = *(const short8*)&vT_s[buf][f * 16 + l16][32 + quad * 8];
        }

        const int n0 = i * 64;
        float4 mv[4];
#pragma unroll
        for (int f = 0; f < 4; f++)
            mv[f] = *(const float4*)&madd_row[n0 + f * 16 + quad * 4];

        // per strip: S^T = K.Q^T (key = f*16+quad*4+r, q = l16, log2 units),
        // P = exp2(S^T + mask) packed round-half-up -> LDS; denominator from
        // the SAME rounded bf16 values (exact num/den consistency)
#pragma unroll
        for (int s = 0; s < 2; s++) {
            floatx4 st[4];
#pragma unroll
            for (int f = 0; f < 4; f++) {
                floatx4 t = (floatx4)0.0f;
                t = __builtin_amdgcn_mfma_f32_16x16x32_bf16(ak[f][0], bq[s][0], t, 0, 0, 0);
                t = __builtin_amdgcn_mfma_f32_16x16x32_bf16(ak[f][1], bq[s][1], t, 0, 0, 0);
                st[f] = t;
            }
            unsigned short* prow = s ? prow1 : prow0;
            float ls = 0.0f;
#pragma unroll
            for (int f = 0; f < 4; f++) {
                float p0 = __builtin_amdgcn_exp2f(st[f][0] + mv[f].x);
                float p1 = __builtin_amdgcn_exp2f(st[f][1] + mv[f].y);
                float p2 = __builtin_amdgcn_exp2f(st[f][2] + mv[f].z);
                float p3 = __builtin_amdgcn_exp2f(st[f][3] + mv[f].w);
                uint2 pw;
                pw.x = pack2bf_rhu(p0, p1);
                pw.y = pack2bf_rhu(p2, p3);
                *(uint2*)&prow[f * 16 + quad * 4] = pw;  // 4 consecutive keys
                float r0 = __builtin_bit_cast(float, pw.x << 16);
                float r1 = __builtin_bit_cast(float, pw.x & 0xffff0000u);
                float r2 = __builtin_bit_cast(float, pw.y << 16);
                float r3 = __builtin_bit_cast(float, pw.y & 0xffff0000u);
                ls += (r0 + r1) + (r2 + r3);
            }
            lsum[s] += ls;
        }

        // drain this wave's P^T writes before aliasing A-frag reads
        asm volatile("s_waitcnt lgkmcnt(0)" ::: "memory");
#pragma unroll
        for (int s = 0; s < 2; s++) {
            const unsigned short* pr = s ? prow1 : prow0;
            short8 ap0 = *(const short8*)&pr[quad * 8];
            short8 ap1 = *(const short8*)&pr[32 + quad * 8];
#pragma unroll
            for (int f = 0; f < 4; f++) {
                o[s][f] = __builtin_amdgcn_mfma_f32_16x16x32_bf16(ap0, bv[f][0], o[s][f], 0, 0, 0);
                o[s][f] = __builtin_amdgcn_mfma_f32_16x16x32_bf16(ap1, bv[f][1], o[s][f], 0, 0, 0);
            }
        }

        if (pf) {
            *(uint4*)&k_s[buf ^ 1][kr][kc]      = pk0;
            *(uint4*)&k_s[buf ^ 1][kr][kc + 8]  = pk1;
            *(uint4*)&vT_s[buf ^ 1][kr][kc]     = pv0;
            *(uint4*)&vT_s[buf ^ 1][kr][kc + 8] = pv1;
        }
    }

    // epilogue: reduce lsum across quads -> L[q = base_s + l16] at all lanes,
    // then fetch L for row quad*4+r via shfl (lives at lane l16' = quad*4+r)
#pragma unroll
    for (int s = 0; s < 2; s++) {
        float t = lsum[s];
        t += __shfl_xor(t, 16);
        t += __shfl_xor(t, 32);
        size_t rowb = (size_t)(b * NQ + m0 + wave * 32 + s * 16);
#pragma unroll
        for (int r = 0; r < 4; r++) {
            float lr = __shfl(t, quad * 4 + r);
            float inv = 1.0f / lr;
            size_t row = rowb + quad * 4 + r;
#pragma unroll
            for (int f = 0; f < 4; f++) {
                unsigned u = __builtin_bit_cast(unsigned, o[s][f][r] * inv) + 0x8000u;
                x[row * DMODEL + h * HD + f * 16 + l16] = (unsigned short)(u >> 16);
            }
        }
    }
}

extern "C" void kernel_launch(void* const* d_in, const int* in_sizes, int n_in,
                              void* d_out, int out_size, void* d_ws, size_t ws_size,
                              hipStream_t stream) {
    const float* q     = (const float*)d_in[0];
    const float* kv    = (const float*)d_in[1];
    const int*   mask  = (const int*)d_in[2];
    const float* Wq    = (const float*)d_in[3];
    const float* Wkv   = (const float*)d_in[4];
    const float* Wproj = (const float*)d_in[5];
    const float* bproj = (const float*)d_in[6];
    float* out = (float*)d_out;

    // ws layout, total 92,340,480 B <= proven 92,540,480 (R2)
    char* ws = (char*)d_ws;
    size_t o = 0;
    o += 256;  // (reserved)
    float* maskadd   = (float*)(ws + o); o += 65536;
    unsigned short* Qb     = (unsigned short*)(ws + o); o += (size_t)BB * NQ * DMODEL * 2;   // 8 MB
    unsigned short* Kb     = (unsigned short*)(ws + o); o += (size_t)BB * NKV * DMODEL * 2;  // 32 MB
    unsigned short* VTb    = (unsigned short*)(ws + o); o += (size_t)BB * NKV * DMODEL * 2;  // 32 MB
    unsigned short* WprojT = (unsigned short*)(ws + o); o += (size_t)DMODEL * DMODEL * 2;    // 2 MB
    unsigned short* qbf    = (unsigned short*)(ws + o);  // 8 MB, dead after q-proj
    unsigned short* xb     = qbf;                        // alias: written by attn later
    o += (size_t)BB * NQ * DMODEL * 2;
    unsigned short* WqT    = (unsigned short*)(ws + o); o += (size_t)DMODEL * DMODEL * 2;     // 2 MB
    unsigned short* WkvT   = (unsigned short*)(ws + o); o += (size_t)DMODEL * 2 * DMODEL * 2; // 4 MB
    unsigned short* kvh = (unsigned short*)d_out;  // kv bf16 staged through d_out

    hipLaunchKernelGGL(maskprep2, dim3(1), dim3(1024), 0, stream, mask, maskadd);
    hipLaunchKernelGGL(transpose_cast3, dim3(32, DMODEL / 64, 3), dim3(256), 0, stream,
                       Wq, Wkv, Wproj, WqT, WkvT, WprojT);

    // Qb = bf16((q @ Wq) * hd^-0.5 * log2(e))  [log2e folded for native exp2]
    hipLaunchKernelGGL(cast_bf16, dim3(BB * NQ * DMODEL / 2048), dim3(256), 0, stream,
                       q, qbf, BB * NQ * DMODEL);
    hipLaunchKernelGGL((gemm_mfma<0>), dim3(DMODEL / 128, BB * NQ / 128), dim3(256), 16384, stream,
                       qbf, WqT, (const float*)nullptr, Qb, (unsigned short*)nullptr,
                       (float*)nullptr, BB * NQ, DMODEL, DMODEL, 0.125f * 1.44269504f, 0);

    // kv projection in two halves, bf16 A staged in d_out
    const int HALF_ROWS = BB * NKV / 2;  // 8192
    for (int half = 0; half < 2; half++) {
        const float* src = kv + (size_t)half * HALF_ROWS * DMODEL;
        hipLaunchKernelGGL(cast_bf16, dim3(HALF_ROWS * DMODEL / 2048), dim3(256), 0, stream,
                           src, kvh, HALF_ROWS * DMODEL);
        hipLaunchKernelGGL((gemm_mfma<1>), dim3(2 * DMODEL / 128, HALF_ROWS / 128), dim3(256), 36864, stream,
                           kvh, WkvT, (const float*)nullptr, Kb, VTb,
                           (float*)nullptr, HALF_ROWS, 2 * DMODEL, DMODEL, 1.0f, half * HALF_ROWS);
    }

    // fused flash attention v6 -> xb (bf16)
    hipLaunchKernelGGL(attn_mfma6, dim3(NQ / 128, BB * NH), dim3(256), 0, stream,
                       Qb, Kb, VTb, maskadd, xb);

    // out = xb @ Wproj + bproj (fp32)
    hipLaunchKernelGGL((gemm_mfma<2>), dim3(DMODEL / 128, BB * NQ / 128), dim3(256), 16384, stream,
                       xb, WprojT, bproj, (unsigned short*)nullptr, (unsigned short*)nullptr,
                       out, BB * NQ, DMODEL, DMODEL, 1.0f, 0);
}

// Round 5
// 410.551 us; speedup vs baseline: 1.1127x; 1.0296x over previous
//
#include <hip/hip_runtime.h>
#include <hip/hip_bf16.h>
#include <math.h>

#define BB 4
#define NQ 1024
#define NKV 4096
#define DMODEL 1024
#define NH 16
#define HD 64

typedef __attribute__((ext_vector_type(8))) short short8;
typedef __attribute__((ext_vector_type(4))) float floatx4;

__device__ __forceinline__ unsigned short f2bf(float f) {
    __hip_bfloat16 b = __float2bfloat16(f);
    return *reinterpret_cast<unsigned short*>(&b);
}

// pack two known-finite positive floats to bf16x2, round-half-up (proven v4-v6)
__device__ __forceinline__ unsigned int pack2bf_rhu(float a, float b) {
    unsigned ua = __builtin_bit_cast(unsigned, a) + 0x8000u;
    unsigned ub = __builtin_bit_cast(unsigned, b) + 0x8000u;
    return (ua >> 16) | (ub & 0xffff0000u);
}

// async global->LDS DMA, 16B/lane. Dest = wave-uniform base + lane*16.
__device__ __forceinline__ void gl_lds16(void* lds, const void* g) {
    __builtin_amdgcn_global_load_lds(
        (const __attribute__((address_space(1))) unsigned int*)g,
        (__attribute__((address_space(3))) unsigned int*)lds, 16, 0, 0);
}

// ---------------- mask: detect format + expand to AND-halfwords ----------------
// output: 0xFFFF = keep, 0x0000 = masked (applied by AND on packed bf16 P)
__global__ __launch_bounds__(1024) void maskprep3(const int* __restrict__ mask,
                                                  unsigned short* __restrict__ maskb) {
    __shared__ int s;
    if (threadIdx.x == 0) s = 0;
    __syncthreads();
    int local = 0;
    for (int i = threadIdx.x; i < 4096; i += 1024)
        if (((const unsigned*)mask)[i] > 1u) local = 1;
    if (local) atomicOr(&s, 1);
    __syncthreads();
    const bool bytes = (s != 0);
    for (int i = threadIdx.x; i < BB * NKV; i += 1024) {
        bool m = bytes ? (((const unsigned char*)mask)[i] != 0) : (mask[i] != 0);
        maskb[i] = m ? (unsigned short)0 : (unsigned short)0xFFFFu;
    }
}

// ---------------- elementwise fp32 -> bf16 cast (8 elems/thread) ----------------
__global__ __launch_bounds__(256) void cast_bf16(const float* __restrict__ src,
                                                 unsigned short* __restrict__ dst,
                                                 int n) {
    int i = (blockIdx.x * 256 + threadIdx.x) * 8;
    if (i >= n) return;
    float4 a = *(const float4*)&src[i];
    float4 b = *(const float4*)&src[i + 4];
    short8 v;
    v[0] = (short)f2bf(a.x); v[1] = (short)f2bf(a.y);
    v[2] = (short)f2bf(a.z); v[3] = (short)f2bf(a.w);
    v[4] = (short)f2bf(b.x); v[5] = (short)f2bf(b.y);
    v[6] = (short)f2bf(b.z); v[7] = (short)f2bf(b.w);
    *(short8*)&dst[i] = v;
}

// ---------------- all 3 weight transposes in ONE launch -------------------------
__global__ __launch_bounds__(256) void transpose_cast3(
    const float* __restrict__ Wq, const float* __restrict__ Wkv,
    const float* __restrict__ Wproj,
    unsigned short* __restrict__ WqT, unsigned short* __restrict__ WkvT,
    unsigned short* __restrict__ WprojT)
{
    const float* src; unsigned short* dst; int N;
    if (blockIdx.z == 0)      { src = Wq;    dst = WqT;    N = DMODEL; }
    else if (blockIdx.z == 1) { src = Wkv;   dst = WkvT;   N = 2 * DMODEL; }
    else                      { src = Wproj; dst = WprojT; N = DMODEL; }
    if ((int)blockIdx.x * 64 >= N) return;
    const int K = DMODEL;
    __shared__ unsigned short t[64][72];
    int r0 = blockIdx.y * 64, c0 = blockIdx.x * 64;
    int tid = threadIdx.x;
#pragma unroll
    for (int i = 0; i < 4; i++) {
        int r = i * 16 + (tid >> 4), c = (tid & 15) * 4;
        float4 v = *(const float4*)&src[(size_t)(r0 + r) * N + c0 + c];
        t[c + 0][r] = f2bf(v.x); t[c + 1][r] = f2bf(v.y);
        t[c + 2][r] = f2bf(v.z); t[c + 3][r] = f2bf(v.w);
    }
    __syncthreads();
#pragma unroll
    for (int i = 0; i < 2; i++) {
        int rr = i * 32 + (tid >> 3), cc = (tid & 7) * 8;
        *(uint4*)&dst[(size_t)(c0 + rr) * K + r0 + cc] = *(uint4*)&t[rr][cc];
    }
}

// ---------------- bf16 MFMA GEMM: C = alpha * A @ Bt^T (proven R3) ----------------
template <int EPI>
__global__ __launch_bounds__(256) void gemm_mfma(
    const unsigned short* __restrict__ A,
    const unsigned short* __restrict__ Bt,
    const float* __restrict__ bias,
    unsigned short* __restrict__ o16,
    unsigned short* __restrict__ oT,
    float* __restrict__ o32,
    int M, int N, int K, float alpha, int m_out_base)
{
    extern __shared__ char smem[];
    unsigned short* As = (unsigned short*)smem;            // 512 chunks = 8KB
    unsigned short* Bs = (unsigned short*)(smem + 8192);   // 512 chunks = 8KB
    const int tid = threadIdx.x;
    const int wave = tid >> 6, lane = tid & 63;
    const int quad = lane >> 4, l16 = lane & 15;
    const int wm = wave >> 1, wn = wave & 1;
    const int m0 = blockIdx.y * 128, n0 = blockIdx.x * 128;

    const int c0 = wave * 64 + lane, c1 = c0 + 256;
    const int r0s = c0 >> 2, cc0 = (c0 & 3) ^ ((r0s >> 2) & 3);
    const int r1s = c1 >> 2, cc1 = (c1 & 3) ^ ((r1s >> 2) & 3);
    const unsigned short* ag0 = A + (size_t)(m0 + r0s) * K + cc0 * 8;
    const unsigned short* ag1 = A + (size_t)(m0 + r1s) * K + cc1 * 8;
    const unsigned short* bg0 = Bt + (size_t)(n0 + r0s) * K + cc0 * 8;
    const unsigned short* bg1 = Bt + (size_t)(n0 + r1s) * K + cc1 * 8;
    char* AldsW0 = (char*)As + (wave * 64) * 16;
    char* AldsW1 = (char*)As + (256 + wave * 64) * 16;
    char* BldsW0 = (char*)Bs + (wave * 64) * 16;
    char* BldsW1 = (char*)Bs + (256 + wave * 64) * 16;

    int achk[4], bchk[4];
#pragma unroll
    for (int i = 0; i < 4; i++) {
        int ra = wm * 64 + i * 16 + l16;
        achk[i] = ra * 4 + (quad ^ ((ra >> 2) & 3));
        int rb = wn * 64 + i * 16 + l16;
        bchk[i] = rb * 4 + (quad ^ ((rb >> 2) & 3));
    }

    floatx4 acc[4][4];
#pragma unroll
    for (int i = 0; i < 4; i++)
#pragma unroll
        for (int j = 0; j < 4; j++) acc[i][j] = (floatx4)0.0f;

    for (int kt = 0; kt < K; kt += 32) {
        __syncthreads();
        gl_lds16(AldsW0, ag0 + kt);
        gl_lds16(AldsW1, ag1 + kt);
        gl_lds16(BldsW0, bg0 + kt);
        gl_lds16(BldsW1, bg1 + kt);
        __syncthreads();
        short8 af[4], bfr[4];
#pragma unroll
        for (int i = 0; i < 4; i++) af[i] = *(const short8*)&As[achk[i] * 8];
#pragma unroll
        for (int j = 0; j < 4; j++) bfr[j] = *(const short8*)&Bs[bchk[j] * 8];
#pragma unroll
        for (int i = 0; i < 4; i++)
#pragma unroll
            for (int j = 0; j < 4; j++)
                acc[i][j] = __builtin_amdgcn_mfma_f32_16x16x32_bf16(
                    af[i], bfr[j], acc[i][j], 0, 0, 0);
    }

    const int rowbase = m0 + wm * 64;
    const int colbase = n0 + wn * 64;
    if (EPI == 0) {
#pragma unroll
        for (int i = 0; i < 4; i++)
#pragma unroll
            for (int r = 0; r < 4; r++) {
                size_t row = (size_t)(rowbase + i * 16 + quad * 4 + r);
#pragma unroll
                for (int j = 0; j < 4; j++)
                    o16[row * N + colbase + j * 16 + l16] =
                        f2bf(acc[i][j][r] * alpha);
            }
    } else if (EPI == 2) {
        float bv[4];
#pragma unroll
        for (int j = 0; j < 4; j++) bv[j] = bias[colbase + j * 16 + l16];
#pragma unroll
        for (int i = 0; i < 4; i++)
#pragma unroll
            for (int r = 0; r < 4; r++) {
                size_t row = (size_t)(rowbase + i * 16 + quad * 4 + r);
#pragma unroll
                for (int j = 0; j < 4; j++)
                    o32[row * N + colbase + j * 16 + l16] = acc[i][j][r] + bv[j];
            }
    } else {  // EPI == 1: N=2048; cols<1024 -> Kb natural, cols>=1024 -> VTb^T
        if (n0 < DMODEL) {
#pragma unroll
            for (int i = 0; i < 4; i++)
#pragma unroll
                for (int r = 0; r < 4; r++) {
                    int gm = m_out_base + rowbase + i * 16 + quad * 4 + r;
                    int b = gm >> 12, key = gm & (NKV - 1);
                    size_t row = (size_t)(b * NKV + key);
#pragma unroll
                    for (int j = 0; j < 4; j++)
                        o16[row * DMODEL + colbase + j * 16 + l16] =
                            f2bf(acc[i][j][r]);
                }
        } else {
            __syncthreads();
            unsigned short (*scr)[72] =
                (unsigned short(*)[72])(smem + wave * 64 * 72 * 2);
#pragma unroll
            for (int i = 0; i < 4; i++)
#pragma unroll
                for (int j = 0; j < 4; j++)
#pragma unroll
                    for (int r = 0; r < 4; r++)
                        scr[j * 16 + l16][i * 16 + quad * 4 + r] =
                            f2bf(acc[i][j][r]);
            __syncthreads();
            int gmb = m_out_base + rowbase;
            int b = gmb >> 12, key0 = gmb & (NKV - 1);
            int d0 = colbase - DMODEL;
#pragma unroll
            for (int p = 0; p < 8; p++) {
                int rr = p * 8 + (lane >> 3), ch = lane & 7;
                *(uint4*)&oT[((size_t)(b * DMODEL + d0 + rr)) * NKV + key0 + ch * 8] =
                    *(uint4*)&scr[rr][ch * 8];
            }
        }
    }
}

// ---------------- fused flash attention v9: proven primitives, 16 waves/CU -----
// v7/v8 (in-register P via permlane/bpermute) both FAILED on unverifiable
// cross-lane instruction semantics -> abandoned. v9 = v6's PROVEN per-wave
// pipeline (P through private LDS rows + lgkm drain) with only lane-local /
// derivation-equal deltas:
//  * 512-thr blocks, 8 waves x 16 q-rows: grid 512 -> 2 blocks x 8 waves =
//    16 waves/CU (4/SIMD), 2x v6's issue slots (v6 was issue-bound at 44%
//    VALU + 23% MFMA with only 2 waves/SIMD).
//  * mask = AND with 0xFFFF/0 halfwords on packed P (lane-local; identical
//    to exp2(s-1e30) which rounds to 0): kills 32 adds + mask float loads.
//  * denominator via all-ones B-frag MFMA on the SAME packed P (v4-proven
//    concept; num/den consistency exact): kills lsum VALU + epilogue shfl.
//  * Q B-frags loaded direct from global — byte-identical addresses to
//    v6's staged read; qp_s now holds P strips only.
//  * prefetch issued AFTER the top barrier (v6 issued just before it ->
//    barrier's vmcnt(0) drain exposed HBM latency), consumed at commit.
//  * s_setprio(1) around both MFMA clusters (T5).
// LDS 55.3KB x 2 blocks = 110.6KB <= 160KB.
__global__ __launch_bounds__(512, 4) void attn_mfma9(
    const unsigned short* __restrict__ Qb,   // (B,NQ,D) bf16, scaled
    const unsigned short* __restrict__ Kb,   // (B,NKV,D) bf16
    const unsigned short* __restrict__ VTb,  // (B,D,NKV) bf16
    const unsigned short* __restrict__ maskb,// (B,NKV) 0xFFFF keep / 0 masked
    unsigned short* __restrict__ x)          // (B,NQ,D) bf16
{
    const int lid = blockIdx.y * gridDim.x + blockIdx.x;  // [0,512)
    const int xcd = lid & 7, slot = lid >> 3;             // slot in [0,64)
    const int bh = xcd * 8 + (slot & 7);    // 8 q-tiles of one (b,h) per XCD
    const int b = bh >> 4, h = bh & 15;
    const int m0 = (slot >> 3) * 128;
    const int tid = threadIdx.x;
    const int wave = tid >> 6, lane = tid & 63;
    const int quad = lane >> 4, l16 = lane & 15;

    __shared__ __align__(16) unsigned short qp_s[128][72];    // P strips only
    __shared__ __align__(16) unsigned short k_s[2][64][72];   // [key][d]
    __shared__ __align__(16) unsigned short vT_s[2][64][72];  // [d][key]

    const unsigned short* Kbase = Kb + ((size_t)b * NKV) * DMODEL + h * HD;
    const unsigned short* Vbase = VTb + ((size_t)(b * DMODEL + h * HD)) * NKV;

    const int kr = tid >> 3, kc = (tid & 7) * 8;  // staging: 1 uint4/thread/array

    // prologue: stage K/V tile 0 into buf 0
    {
        uint4 a0 = *(const uint4*)(Kbase + (size_t)kr * DMODEL + kc);
        uint4 b0 = *(const uint4*)(Vbase + (size_t)kr * NKV + kc);
        *(uint4*)&k_s[0][kr][kc]  = a0;
        *(uint4*)&vT_s[0][kr][kc] = b0;
    }

    // Q B-frags direct from global (derivation-equal to v6's staged read)
    const unsigned short* qsrc =
        Qb + ((size_t)(b * NQ + m0 + wave * 16 + l16)) * DMODEL + h * HD + quad * 8;
    short8 bq0 = *(const short8*)qsrc;
    short8 bq1 = *(const short8*)(qsrc + 32);

    const unsigned short* mrow = maskb + b * NKV;
    unsigned short* prow = &qp_s[wave * 16 + l16][0];

    short8 ones;
#pragma unroll
    for (int e = 0; e < 8; e++) ones[e] = (short)0x3F80;  // bf16 1.0

    floatx4 o[4], ol;
#pragma unroll
    for (int f = 0; f < 4; f++) o[f] = (floatx4)0.0f;
    ol = (floatx4)0.0f;

    __syncthreads();  // tile 0 staged

    for (int i = 0; i < NKV / 64; i++) {
        const int buf = i & 1;
        const bool pf = (i < NKV / 64 - 1);
        if (i) __syncthreads();  // commit of buf (prev iter) visible

        // prefetch next tile into regs AFTER the barrier: in flight across
        // the whole iteration, consumed at the commit below
        uint4 pk, pv;
        if (pf) {
            int nn = (i + 1) * 64;
            pk = *(const uint4*)(Kbase + (size_t)(nn + kr) * DMODEL + kc);
            pv = *(const uint4*)(Vbase + (size_t)kr * NKV + nn + kc);
        }

        // mask AND-words for keys f*16+quad*4+{0..3}
        uint2 mw[4];
#pragma unroll
        for (int f = 0; f < 4; f++)
            mw[f] = *(const uint2*)&mrow[i * 64 + f * 16 + quad * 4];

        // S^T = K.Q^T : key = f*16+quad*4+r, q = l16 (log2 units)
        floatx4 st[4];
        __builtin_amdgcn_s_setprio(1);
#pragma unroll
        for (int f = 0; f < 4; f++) {
            short8 ak0 = *(const short8*)&k_s[buf][f * 16 + l16][quad * 8];
            short8 ak1 = *(const short8*)&k_s[buf][f * 16 + l16][32 + quad * 8];
            floatx4 t = (floatx4)0.0f;
            t = __builtin_amdgcn_mfma_f32_16x16x32_bf16(ak0, bq0, t, 0, 0, 0);
            t = __builtin_amdgcn_mfma_f32_16x16x32_bf16(ak1, bq1, t, 0, 0, 0);
            st[f] = t;
        }
        __builtin_amdgcn_s_setprio(0);

        // P = exp2(S^T) packed bf16, masked by AND, written to private LDS row
#pragma unroll
        for (int f = 0; f < 4; f++) {
            float p0 = __builtin_amdgcn_exp2f(st[f][0]);
            float p1 = __builtin_amdgcn_exp2f(st[f][1]);
            float p2 = __builtin_amdgcn_exp2f(st[f][2]);
            float p3 = __builtin_amdgcn_exp2f(st[f][3]);
            uint2 pw;
            pw.x = pack2bf_rhu(p0, p1) & mw[f].x;
            pw.y = pack2bf_rhu(p2, p3) & mw[f].y;
            *(uint2*)&prow[f * 16 + quad * 4] = pw;  // 4 consecutive keys
        }

        // drain this wave's P writes before aliasing A-frag reads (proven v4-v6)
        asm volatile("s_waitcnt lgkmcnt(0)" ::: "memory");
        short8 ap0 = *(const short8*)&prow[quad * 8];
        short8 ap1 = *(const short8*)&prow[32 + quad * 8];

        // O += P.V ; l += P.1 (ones B-frag => ol[r] = L[q=quad*4+r] at all lanes)
        __builtin_amdgcn_s_setprio(1);
#pragma unroll
        for (int f = 0; f < 4; f++) {
            short8 bv0 = *(const short8*)&vT_s[buf][f * 16 + l16][quad * 8];
            short8 bv1 = *(const short8*)&vT_s[buf][f * 16 + l16][32 + quad * 8];
            o[f] = __builtin_amdgcn_mfma_f32_16x16x32_bf16(ap0, bv0, o[f], 0, 0, 0);
            o[f] = __builtin_amdgcn_mfma_f32_16x16x32_bf16(ap1, bv1, o[f], 0, 0, 0);
        }
        ol = __builtin_amdgcn_mfma_f32_16x16x32_bf16(ap0, ones, ol, 0, 0, 0);
        ol = __builtin_amdgcn_mfma_f32_16x16x32_bf16(ap1, ones, ol, 0, 0, 0);
        __builtin_amdgcn_s_setprio(0);

        // commit prefetched tile into the other buffer
        if (pf) {
            *(uint4*)&k_s[buf ^ 1][kr][kc]  = pk;
            *(uint4*)&vT_s[buf ^ 1][kr][kc] = pv;
        }
    }

    // epilogue: ol[r] = L for q-row quad*4+r (identical at every lane)
#pragma unroll
    for (int r = 0; r < 4; r++) {
        float inv = 1.0f / ol[r];
        size_t row = (size_t)(b * NQ + m0 + wave * 16 + quad * 4 + r);
#pragma unroll
        for (int f = 0; f < 4; f++) {
            unsigned u = __builtin_bit_cast(unsigned, o[f][r] * inv) + 0x8000u;
            x[row * DMODEL + h * HD + f * 16 + l16] = (unsigned short)(u >> 16);
        }
    }
}

extern "C" void kernel_launch(void* const* d_in, const int* in_sizes, int n_in,
                              void* d_out, int out_size, void* d_ws, size_t ws_size,
                              hipStream_t stream) {
    const float* q     = (const float*)d_in[0];
    const float* kv    = (const float*)d_in[1];
    const int*   mask  = (const int*)d_in[2];
    const float* Wq    = (const float*)d_in[3];
    const float* Wkv   = (const float*)d_in[4];
    const float* Wproj = (const float*)d_in[5];
    const float* bproj = (const float*)d_in[6];
    float* out = (float*)d_out;

    // ws layout, total <= proven 92,540,480 (R2)
    char* ws = (char*)d_ws;
    size_t o = 0;
    o += 256;  // (reserved)
    unsigned short* maskb  = (unsigned short*)(ws + o); o += 65536;  // 32KB used
    unsigned short* Qb     = (unsigned short*)(ws + o); o += (size_t)BB * NQ * DMODEL * 2;   // 8 MB
    unsigned short* Kb     = (unsigned short*)(ws + o); o += (size_t)BB * NKV * DMODEL * 2;  // 32 MB
    unsigned short* VTb    = (unsigned short*)(ws + o); o += (size_t)BB * NKV * DMODEL * 2;  // 32 MB
    unsigned short* WprojT = (unsigned short*)(ws + o); o += (size_t)DMODEL * DMODEL * 2;    // 2 MB
    unsigned short* qbf    = (unsigned short*)(ws + o);  // 8 MB, dead after q-proj
    unsigned short* xb     = qbf;                        // alias: written by attn later
    o += (size_t)BB * NQ * DMODEL * 2;
    unsigned short* WqT    = (unsigned short*)(ws + o); o += (size_t)DMODEL * DMODEL * 2;     // 2 MB
    unsigned short* WkvT   = (unsigned short*)(ws + o); o += (size_t)DMODEL * 2 * DMODEL * 2; // 4 MB
    unsigned short* kvh = (unsigned short*)d_out;  // kv bf16 staged through d_out

    hipLaunchKernelGGL(maskprep3, dim3(1), dim3(1024), 0, stream, mask, maskb);
    hipLaunchKernelGGL(transpose_cast3, dim3(32, DMODEL / 64, 3), dim3(256), 0, stream,
                       Wq, Wkv, Wproj, WqT, WkvT, WprojT);

    // Qb = bf16((q @ Wq) * hd^-0.5 * log2(e))  [log2e folded for native exp2]
    hipLaunchKernelGGL(cast_bf16, dim3(BB * NQ * DMODEL / 2048), dim3(256), 0, stream,
                       q, qbf, BB * NQ * DMODEL);
    hipLaunchKernelGGL((gemm_mfma<0>), dim3(DMODEL / 128, BB * NQ / 128), dim3(256), 16384, stream,
                       qbf, WqT, (const float*)nullptr, Qb, (unsigned short*)nullptr,
                       (float*)nullptr, BB * NQ, DMODEL, DMODEL, 0.125f * 1.44269504f, 0);

    // kv projection in two halves, bf16 A staged in d_out
    const int HALF_ROWS = BB * NKV / 2;  // 8192
    for (int half = 0; half < 2; half++) {
        const float* src = kv + (size_t)half * HALF_ROWS * DMODEL;
        hipLaunchKernelGGL(cast_bf16, dim3(HALF_ROWS * DMODEL / 2048), dim3(256), 0, stream,
                           src, kvh, HALF_ROWS * DMODEL);
        hipLaunchKernelGGL((gemm_mfma<1>), dim3(2 * DMODEL / 128, HALF_ROWS / 128), dim3(256), 36864, stream,
                           kvh, WkvT, (const float*)nullptr, Kb, VTb,
                           (float*)nullptr, HALF_ROWS, 2 * DMODEL, DMODEL, 1.0f, half * HALF_ROWS);
    }

    // fused flash attention v9 -> xb (bf16)
    hipLaunchKernelGGL(attn_mfma9, dim3(NQ / 128, BB * NH), dim3(512), 0, stream,
                       Qb, Kb, VTb, maskb, xb);

    // out = xb @ Wproj + bproj (fp32)
    hipLaunchKernelGGL((gemm_mfma<2>), dim3(DMODEL / 128, BB * NQ / 128), dim3(256), 16384, stream,
                       xb, WprojT, bproj, (unsigned short*)nullptr, (unsigned short*)nullptr,
                       out, BB * NQ, DMODEL, DMODEL, 1.0f, 0);
}